// Round 1
// baseline (437.284 us; speedup 1.0000x reference)
//
#include <hip/hip_runtime.h>

typedef _Float16 f16;
typedef _Float16 f16x4 __attribute__((ext_vector_type(4)));
typedef _Float16 f16x8 __attribute__((ext_vector_type(8)));
typedef float    f32x4 __attribute__((ext_vector_type(4)));

#define MFMA_F16(a,b,c) __builtin_amdgcn_mfma_f32_16x16x32_f16((a),(b),(c),0,0,0)

// ---------------- FFT-layout matrices (exact 0/+-1 entries) ----------------
// x chunk index cc = c*4 + d*2 + e  (c in [0,4), d in [0,2), e = re/im)
// out index    rr = p*4 + f         (f<2: Re at q=f; f>=2: Im at q=f-2)
__device__ __forceinline__ float T_val(int rr, int cc) {
  int p = rr >> 2, f = rr & 3;
  int c = cc >> 2, d = (cc >> 1) & 1, e = cc & 1;
  int q = f & 1;
  int m = (p * c + 2 * q * d) & 3;           // theta = (pi/2)*m
  float cs = (m == 0) ? 1.f : (m == 2) ? -1.f : 0.f;
  float sn = (m == 1) ? 1.f : (m == 3) ? -1.f : 0.f;
  if (f < 2) return (e == 0) ? cs : sn;      // Re(z*e^{-i t}) = vr*cos + vi*sin
  return (e == 0) ? -sn : cs;                // Im(z*e^{-i t}) = -vr*sin + vi*cos
}
__device__ __forceinline__ float U_val(int rr, int cc) {
  int p = rr >> 2, f = rr & 3;
  int c = cc >> 2, d = (cc >> 1) & 1, e = cc & 1;
  int q = f & 1;
  int m = (p * c + 2 * q * d) & 3;           // e^{+i theta}, scaled 1/8
  float cs = (m == 0) ? 1.f : (m == 2) ? -1.f : 0.f;
  float sn = (m == 1) ? 1.f : (m == 3) ? -1.f : 0.f;
  float v;
  if (f < 2) v = (e == 0) ? cs : -sn;        // Re(z*e^{+i t}) = vr*cos - vi*sin
  else       v = (e == 0) ? sn : cs;         // Im = vr*sin + vi*cos
  return v * 0.125f;
}

// ---------------- P1: Wq_eff / Wk_eff (fp32).  grid 4096 = 2*8*256, 256 thr
__global__ void prep_qk(const float* __restrict__ Wq, const float* __restrict__ Wk,
                        float* __restrict__ WqE, float* __restrict__ WkE) {
  int b = blockIdx.x;
  int isK = b >> 11;
  int h = (b >> 8) & 7;
  int dd = b & 255;
  const float* W = isK ? Wk : Wq;
  float* E = isK ? WkE : WqE;
  int k = threadIdx.x;
  size_t base = (size_t)h * 65536;
  float v;
  if (h < 3) {
    v = W[base + (size_t)dd * 256 + k];
  } else {
    int g = dd >> 4, i = dd & 15;
    float s = 0.f;
    for (int ip = 0; ip < 16; ++ip) {
      float t = T_val(ip, i);
      if (t != 0.f) s += t * W[base + (size_t)(g * 16 + ip) * 256 + k];
    }
    v = s;
  }
  E[base + (size_t)dd * 256 + k] = v;
}

// ---------------- P2: Mt[h][d'][d] = (Wq_eff . Wk_eff^T)[d][d'] / 16  (fp16)
// grid 512 = 8 * 8 * 8 (h, d'tile, dtile of 32), 256 thr
__global__ void prep_m(const float* __restrict__ WqE, const float* __restrict__ WkE,
                       f16* __restrict__ Mt) {
  __shared__ float Aq[32][33];
  __shared__ float Bk[32][33];
  int h = blockIdx.x >> 6;
  int dpt = (blockIdx.x >> 3) & 7;   // d' tile
  int dt = blockIdx.x & 7;           // d tile
  int tid = threadIdx.x;
  int drow = tid & 31;               // d within tile
  int dprow4 = (tid >> 5) * 4;       // d' group of 4
  float acc0 = 0.f, acc1 = 0.f, acc2 = 0.f, acc3 = 0.f;
  int r = tid >> 3;
  int c0 = (tid & 7) * 4;
  for (int kt = 0; kt < 8; ++kt) {
    for (int j = 0; j < 4; ++j) {
      Aq[r][c0 + j] = WqE[(size_t)h * 65536 + (size_t)(dt * 32 + r) * 256 + kt * 32 + c0 + j];
      Bk[r][c0 + j] = WkE[(size_t)h * 65536 + (size_t)(dpt * 32 + r) * 256 + kt * 32 + c0 + j];
    }
    __syncthreads();
    #pragma unroll
    for (int k = 0; k < 32; ++k) {
      float a = Aq[drow][k];
      acc0 += a * Bk[dprow4 + 0][k];
      acc1 += a * Bk[dprow4 + 1][k];
      acc2 += a * Bk[dprow4 + 2][k];
      acc3 += a * Bk[dprow4 + 3][k];
    }
    __syncthreads();
  }
  int d_ = dt * 32 + drow;
  size_t ob = (size_t)h * 65536 + (size_t)(dpt * 32 + dprow4) * 256 + d_;
  Mt[ob + 0 * 256] = (f16)(acc0 * 0.0625f);
  Mt[ob + 1 * 256] = (f16)(acc1 * 0.0625f);
  Mt[ob + 2 * 256] = (f16)(acc2 * 0.0625f);
  Mt[ob + 3 * 256] = (f16)(acc3 * 0.0625f);
}

// ---------------- P3: Wvt[h][k'][d] = ((T~^T Wv U~^T)/8)[d][k']  (fp16)
// grid 2048 = 8*256 (h, k'), 256 thr (= d)
__global__ void prep_v(const float* __restrict__ Wv, f16* __restrict__ Wvt) {
  __shared__ float Ts[16][16];
  __shared__ float Us[16][16];
  int h = blockIdx.x >> 8;
  int kp = blockIdx.x & 255;
  int tid = threadIdx.x;
  Ts[tid >> 4][tid & 15] = T_val(tid >> 4, tid & 15);
  Us[tid >> 4][tid & 15] = U_val(tid >> 4, tid & 15);
  __syncthreads();
  int d = tid;
  int g = d >> 4, i = d & 15;
  int gp = kp >> 4, fp = kp & 15;
  float s = 0.f;
  if (h < 3) {
    s = Wv[(size_t)h * 65536 + (size_t)d * 256 + kp];
  } else {
    for (int ip = 0; ip < 16; ++ip) {
      float tv = Ts[ip][i];
      if (tv != 0.f) {
        float inner = 0.f;
        for (int j = 0; j < 16; ++j) {
          float uv = Us[fp][j];
          if (uv != 0.f)
            inner += uv * Wv[(size_t)h * 65536 + (size_t)(g * 16 + ip) * 256 + gp * 16 + j];
        }
        s += tv * inner;
      }
    }
  }
  Wvt[(size_t)h * 65536 + (size_t)kp * 256 + d] = (f16)(s * 0.125f);
}

// ---------------- Main fused kernel ----------------
// grid 1024 (4 batches/block), 512 threads (8 waves), 145408 B dynamic LDS.
// LDS: Xs[128][256] f16 swizzled (64K) | Buf: Y[128][256] swz (64K) / VT[256][136] (68K) | Aat[4][32][40] (10K)
__device__ __forceinline__ int swz(int row, int col) { return col ^ ((row & 7) << 3); }

__global__ __launch_bounds__(512, 2) void mha_main(
    const float* __restrict__ xg_all,
    const f16* __restrict__ MtG,
    const f16* __restrict__ WvtG,
    float* __restrict__ outG)
{
  extern __shared__ char smem[];
  f16* Xs  = (f16*)smem;               // [128][256] swizzled
  f16* Y   = (f16*)(smem + 65536);     // [128][256] swizzled
  f16* VT  = (f16*)(smem + 65536);     // [256][136] (reuses Y buffer)
  f16* Aat = (f16*)(smem + 135168);    // [4][32][40]

  const int tid = threadIdx.x;
  const int w   = tid >> 6;
  const int l   = tid & 63;
  const int l15 = l & 15;
  const int l4  = l >> 4;

  // persistent out^T accumulators: wave -> (batch bo = w>>1, k'-half kh = w&1)
  f32x4 acc[8][2];
  #pragma unroll
  for (int i = 0; i < 8; ++i) {
    acc[i][0] = (f32x4){0.f, 0.f, 0.f, 0.f};
    acc[i][1] = (f32x4){0.f, 0.f, 0.f, 0.f};
  }

  // ---- stage x (4 batches, fp32 -> fp16, swizzled) ----
  const float* xg = xg_all + (size_t)blockIdx.x * 32768;
  #pragma unroll
  for (int i = 0; i < 16; ++i) {
    int f4 = i * 512 + tid;            // float4 index; one row per 64 lanes
    int row = f4 >> 6;
    int col = (f4 & 63) << 2;
    f32x4 v = *(const f32x4*)(xg + (size_t)f4 * 4);
    f16x4 hv = __builtin_convertvector(v, f16x4);
    *(f16x4*)(Xs + row * 256 + swz(row, col)) = hv;
  }
  __syncthreads();

  for (int h = 0; h < 8; ++h) {
    const f16* MtH = MtG + (size_t)h * 65536;
    const f16* WvH = WvtG + (size_t)h * 65536;

    // ---- GEMM1a: Y^T = Mt . X^T  (C rows = d', cols = s'); wave owns 32 d'-rows
    f32x4 C0[8], C1[8];
    #pragma unroll
    for (int nt = 0; nt < 8; ++nt) {
      C0[nt] = (f32x4){0.f, 0.f, 0.f, 0.f};
      C1[nt] = (f32x4){0.f, 0.f, 0.f, 0.f};
    }
    {
      int arow = w * 32 + l15;
      #pragma unroll
      for (int kt = 0; kt < 8; ++kt) {
        int ks = kt * 32 + l4 * 8;
        f16x8 a0 = *(const f16x8*)(MtH + (size_t)arow * 256 + ks);
        f16x8 a1 = *(const f16x8*)(MtH + (size_t)(arow + 16) * 256 + ks);
        #pragma unroll
        for (int nt = 0; nt < 8; ++nt) {
          int xrow = nt * 16 + l15;
          f16x8 b = *(const f16x8*)(Xs + xrow * 256 + swz(xrow, ks));
          C0[nt] = MFMA_F16(a0, b, C0[nt]);
          C1[nt] = MFMA_F16(a1, b, C1[nt]);
        }
      }
      // write Y[s'][d'] (4 consecutive d' per lane per frag)
      #pragma unroll
      for (int nt = 0; nt < 8; ++nt) {
        int srow = nt * 16 + l15;
        int dc0 = w * 32 + l4 * 4;
        *(f16x4*)(Y + srow * 256 + swz(srow, dc0)) = __builtin_convertvector(C0[nt], f16x4);
        *(f16x4*)(Y + srow * 256 + swz(srow, dc0 + 16)) = __builtin_convertvector(C1[nt], f16x4);
      }
    }
    __syncthreads();   // Y visible

    // ---- scores + parity softmax: wave -> (batch bq = w>>1, row-half mt = w&1)
    {
      int bq = w >> 1, mt = w & 1;
      f32x4 S0 = (f32x4){0.f, 0.f, 0.f, 0.f};
      f32x4 S1 = (f32x4){0.f, 0.f, 0.f, 0.f};
      int yrow = bq * 32 + mt * 16 + l15;
      int x0 = bq * 32 + l15;
      int x1 = bq * 32 + 16 + l15;
      #pragma unroll
      for (int kt = 0; kt < 8; ++kt) {
        int ks = kt * 32 + l4 * 8;
        f16x8 ay = *(const f16x8*)(Y + yrow * 256 + swz(yrow, ks));
        f16x8 b0 = *(const f16x8*)(Xs + x0 * 256 + swz(x0, ks));
        f16x8 b1 = *(const f16x8*)(Xs + x1 * 256 + swz(x1, ks));
        S0 = MFMA_F16(ay, b0, S0);
        S1 = MFMA_F16(ay, b1, S1);
      }
      #pragma unroll
      for (int r = 0; r < 4; ++r) {
        bool valid = ((l & 1) == (r & 1));      // t parity == s parity
        float v0 = valid ? S0[r] : -1e30f;
        float v1 = valid ? S1[r] : -1e30f;
        float mx = fmaxf(v0, v1);
        mx = fmaxf(mx, __shfl_xor(mx, 1));
        mx = fmaxf(mx, __shfl_xor(mx, 2));
        mx = fmaxf(mx, __shfl_xor(mx, 4));
        mx = fmaxf(mx, __shfl_xor(mx, 8));
        float e0 = valid ? __expf(v0 - mx) : 0.f;
        float e1 = valid ? __expf(v1 - mx) : 0.f;
        float sm = e0 + e1;
        sm += __shfl_xor(sm, 1);
        sm += __shfl_xor(sm, 2);
        sm += __shfl_xor(sm, 4);
        sm += __shfl_xor(sm, 8);
        float inv = 1.f / sm;
        int s = mt * 16 + l4 * 4 + r;
        Aat[(bq * 32 + s) * 40 + l15] = (f16)(e0 * inv);
        Aat[(bq * 32 + s) * 40 + 16 + l15] = (f16)(e1 * inv);
      }
    }
    __syncthreads();   // all Y reads done (buffer reuse), Aat visible

    // ---- GEMM1b: V = X . Wv_eff  -> VT[k'][s']; wave owns 32 k'-cols
    f32x4 Cv0[8], Cv1[8];
    #pragma unroll
    for (int mt = 0; mt < 8; ++mt) {
      Cv0[mt] = (f32x4){0.f, 0.f, 0.f, 0.f};
      Cv1[mt] = (f32x4){0.f, 0.f, 0.f, 0.f};
    }
    {
      int bcol = w * 32 + l15;
      #pragma unroll
      for (int kt = 0; kt < 8; ++kt) {
        int ks = kt * 32 + l4 * 8;
        f16x8 b0 = *(const f16x8*)(WvH + (size_t)bcol * 256 + ks);
        f16x8 b1 = *(const f16x8*)(WvH + (size_t)(bcol + 16) * 256 + ks);
        #pragma unroll
        for (int mt = 0; mt < 8; ++mt) {
          int xrow = mt * 16 + l15;
          f16x8 a = *(const f16x8*)(Xs + xrow * 256 + swz(xrow, ks));
          Cv0[mt] = MFMA_F16(a, b0, Cv0[mt]);
          Cv1[mt] = MFMA_F16(a, b1, Cv1[mt]);
        }
      }
      #pragma unroll
      for (int mt = 0; mt < 8; ++mt) {
        int sp = mt * 16 + l4 * 4;
        int kp0 = w * 32 + l15;
        *(f16x4*)(VT + kp0 * 136 + sp) = __builtin_convertvector(Cv0[mt], f16x4);
        *(f16x4*)(VT + (kp0 + 16) * 136 + sp) = __builtin_convertvector(Cv1[mt], f16x4);
      }
    }
    __syncthreads();   // VT visible

    // ---- out^T += V^T . A^T : wave -> (batch bo = w>>1, k'-half kh = w&1)
    {
      int bo = w >> 1, kh = w & 1;
      f16x8 bf0 = *(const f16x8*)(Aat + (bo * 32 + l15) * 40 + l4 * 8);
      f16x8 bf1 = *(const f16x8*)(Aat + (bo * 32 + 16 + l15) * 40 + l4 * 8);
      #pragma unroll
      for (int mt = 0; mt < 8; ++mt) {
        int kp = kh * 128 + mt * 16 + l15;
        f16x8 av = *(const f16x8*)(VT + kp * 136 + bo * 32 + l4 * 8);
        acc[mt][0] = MFMA_F16(av, bf0, acc[mt][0]);
        acc[mt][1] = MFMA_F16(av, bf1, acc[mt][1]);
      }
    }
    __syncthreads();   // Buf free for next head
  }

  // ---- store out (fp32, dwordx4): out^T frag -> 4 consecutive k' per lane
  {
    int bo = w >> 1, kh = w & 1;
    float* outB = outG + ((size_t)blockIdx.x * 4 + bo) * 8192;
    #pragma unroll
    for (int mt = 0; mt < 8; ++mt) {
      #pragma unroll
      for (int nt = 0; nt < 2; ++nt) {
        int s = nt * 16 + l15;
        int kp = kh * 128 + mt * 16 + l4 * 4;
        *(f32x4*)(outB + s * 256 + kp) = acc[mt][nt];
      }
    }
  }
}

// ---------------- launch ----------------
extern "C" void kernel_launch(void* const* d_in, const int* in_sizes, int n_in,
                              void* d_out, int out_size, void* d_ws, size_t ws_size,
                              hipStream_t stream) {
  const float* x  = (const float*)d_in[0];
  const float* Wq = (const float*)d_in[1];
  const float* Wk = (const float*)d_in[2];
  const float* Wv = (const float*)d_in[3];
  float* out = (float*)d_out;
  char* ws = (char*)d_ws;
  float* WqE = (float*)ws;                       // 2 MB
  float* WkE = (float*)(ws + 2097152);           // 2 MB
  f16*   Mt  = (f16*)(ws + 4194304);             // 1 MB fp16
  f16*   Wvt = (f16*)(ws + 5242880);             // 1 MB fp16

  prep_qk<<<4096, 256, 0, stream>>>(Wq, Wk, WqE, WkE);
  prep_m<<<512, 256, 0, stream>>>(WqE, WkE, Mt);
  prep_v<<<2048, 256, 0, stream>>>(Wv, Wvt);
  mha_main<<<1024, 512, 145408, stream>>>(x, Mt, Wvt, out);
}